// Round 5
// baseline (23.625 us; speedup 1.0000x reference)
//
#include <hip/hip_runtime.h>
#include <hip/hip_bf16.h>

#define TT 1024
#define AA 16
#define DTS 0.4f
#define EPSV 1e-6f

typedef float f4 __attribute__((ext_vector_type(4)));

// dd components (x,y) of (ado-ado_wo)'' for flat row `row` at time t; 0 at ends
__device__ __forceinline__ float2 dd2(const float2* __restrict__ A,
                                      const float2* __restrict__ B,
                                      int row, int t) {
    if (t <= 0 || t >= TT - 1) return make_float2(0.f, 0.f);
    const float2* a = A + row * TT + t;
    const float2* b = B + row * TT + t;
    float2 am = a[-1], a0 = a[0], ap = a[1];
    float2 bm = b[-1], b0 = b[0], bp = b[1];
    const float s = 1.0f / (DTS * DTS);
    float2 r;
    r.x = ((am.x - bm.x) - 2.f * (a0.x - b0.x) + (ap.x - bp.x)) * s;
    r.y = ((am.y - bm.y) - 2.f * (a0.y - b0.y) + (ap.y - bp.y)) * s;
    return r;
}

// Block = (j, 64-wide t-chunk): 16*16 = 256 blocks, 4 waves = 4 a/m-quarters.
// Lane = t offset -> all global loads coalesced float2 along t.
// ws[t*32+j*2+c] = w[j,t]*s[j,t,c];  coef[u] = ws[u+1] - 2*ws[u]
__global__ __launch_bounds__(256) void wscoef_kernel(const float* __restrict__ ado,
                                                     const float* __restrict__ ado_wo,
                                                     float* __restrict__ ws,
                                                     float* __restrict__ coef) {
    const int bid = blockIdx.x;
    const int j = bid >> 4;
    const int chunk = bid & 15;
    const int tid = threadIdx.x;
    const int sub = tid >> 6;      // wave = a/m quarter
    const int lane = tid & 63;
    const int t = chunk * 64 + lane;
    const int tb = chunk * 64 + 64;     // boundary t (next chunk's first slice)
    const float2* A = (const float2*)ado;
    const float2* B = (const float2*)ado_wo;

    float w = 0.f, sx = 0.f, sy = 0.f;
    float wb = 0.f, sbx = 0.f, sby = 0.f;

    #pragma unroll
    for (int q = 0; q < 4; ++q) {
        int a = sub * 4 + q;
        int rowW = a * AA + j;   // w: reduce over first index
        float2 d = dd2(A, B, rowW, t);
        float n = sqrtf(d.x * d.x + d.y * d.y);
        w += (n < EPSV) ? 0.f : 1.f / n;
        int rowS = j * AA + a;   // s: reduce over second index
        float2 e = dd2(A, B, rowS, t);
        sx += e.x; sy += e.y;
        if (tb < TT) {           // uniform-address (broadcast) loads
            float2 db = dd2(A, B, rowW, tb);
            float nb = sqrtf(db.x * db.x + db.y * db.y);
            wb += (nb < EPSV) ? 0.f : 1.f / nb;
            float2 eb = dd2(A, B, rowS, tb);
            sbx += eb.x; sby += eb.y;
        }
    }

    __shared__ float lw[4][64], lsx[4][64], lsy[4][64];
    __shared__ float lwb[4], lsbx[4], lsby[4];
    lw[sub][lane] = w; lsx[sub][lane] = sx; lsy[sub][lane] = sy;
    if (lane == 0) { lwb[sub] = wb; lsbx[sub] = sbx; lsby[sub] = sby; }
    __syncthreads();

    if (tid < 64) {
        float W  = lw[0][tid] + lw[1][tid] + lw[2][tid] + lw[3][tid];
        float SX = lsx[0][tid] + lsx[1][tid] + lsx[2][tid] + lsx[3][tid];
        float SY = lsy[0][tid] + lsy[1][tid] + lsy[2][tid] + lsy[3][tid];
        float wsx = W * SX, wsy = W * SY;

        float WB  = lwb[0] + lwb[1] + lwb[2] + lwb[3];
        float wbx = WB * (lsbx[0] + lsbx[1] + lsbx[2] + lsbx[3]);
        float wby = WB * (lsby[0] + lsby[1] + lsby[2] + lsby[3]);

        int tt = chunk * 64 + tid;
        *(float2*)(ws + tt * 32 + j * 2) = make_float2(wsx, wsy);

        float nx = __shfl_down(wsx, 1, 64);
        float ny = __shfl_down(wsy, 1, 64);
        if (tid == 63) { nx = wbx; ny = wby; }
        float cx = nx - 2.f * wsx;
        float cy = ny - 2.f * wsy;
        if (tt == TT - 1) { cx = 0.f; cy = 0.f; }  // coef[T-1] unused
        *(float2*)(coef + tt * 32 + j * 2) = make_float2(cx, cy);
    }
}

// out[2k+c] = sum_{u=k-1}^{T-2} sum_j pg[k,u,j,c]*coef[u,j,c]
//           + sum_j pg[k,k-2,j,c]*ws[k-1,j,c]   (k>=2 boundary slice)
// Block b handles k1=b+1 and k2=1023-b simultaneously (two interleaved
// HBM streams, equal total work ~= 1024 slices per block).
__global__ __launch_bounds__(512) void grad_kernel(const float* __restrict__ pg,
                                                   const float* __restrict__ ws,
                                                   const float* __restrict__ coef,
                                                   float* __restrict__ out) {
    const int b = blockIdx.x;
    const int tid = threadIdx.x;
    __shared__ float red[8][4];

    if (b == 0 && tid < 2) out[tid] = 0.0f;  // k = 0 masked out

    const int k1 = b + 1;          // 1..512
    const int k2 = TT - 1 - b;     // 1023..512
    const bool dup = (k1 == k2);   // b == 511

    const f4* __restrict__ row1 = (const f4*)(pg + (size_t)k1 * (TT * AA * 2));
    const f4* __restrict__ row2 = (const f4*)(pg + (size_t)k2 * (TT * AA * 2));
    const f4* __restrict__ coef4 = (const f4*)coef;
    const f4* __restrict__ ws4 = (const f4*)ws;

    const int base1 = (k1 - 1) * 8;
    const int base2 = (k2 - 1) * 8;
    const int end = (TT - 1) * 8;
    const int n1 = end - base1;    // (1024-k1)*8  >= n2
    const int n2 = end - base2;

    float ax1 = 0.f, ay1 = 0.f, ax2 = 0.f, ay2 = 0.f;

    // boundary slices u = k-2 (coefficient ws[k-1])
    if (tid < 8) {
        if (k1 >= 2) {
            f4 p  = __builtin_nontemporal_load(&row1[(k1 - 2) * 8 + tid]);
            f4 wv = ws4[(k1 - 1) * 8 + tid];
            ax1 += p.x * wv.x + p.z * wv.z;
            ay1 += p.y * wv.y + p.w * wv.w;
        }
        if (!dup) {  // k2 >= 512 so k2 >= 2 always
            f4 p  = __builtin_nontemporal_load(&row2[(k2 - 2) * 8 + tid]);
            f4 wv = ws4[(k2 - 1) * 8 + tid];
            ax2 += p.x * wv.x + p.z * wv.z;
            ay2 += p.y * wv.y + p.w * wv.w;
        }
    }

    // main: two interleaved suffix streams
    #pragma unroll 2
    for (int o = tid; o < n1; o += 512) {
        f4 p1 = __builtin_nontemporal_load(&row1[base1 + o]);
        f4 c1 = coef4[base1 + o];
        ax1 += p1.x * c1.x + p1.z * c1.z;
        ay1 += p1.y * c1.y + p1.w * c1.w;
        if (!dup && o < n2) {
            f4 p2 = __builtin_nontemporal_load(&row2[base2 + o]);
            f4 c2 = coef4[base2 + o];
            ax2 += p2.x * c2.x + p2.z * c2.z;
            ay2 += p2.y * c2.y + p2.w * c2.w;
        }
    }

    // wave64 shuffle reduce (4 values)
    for (int off = 32; off > 0; off >>= 1) {
        ax1 += __shfl_down(ax1, off, 64);
        ay1 += __shfl_down(ay1, off, 64);
        ax2 += __shfl_down(ax2, off, 64);
        ay2 += __shfl_down(ay2, off, 64);
    }
    int wave = tid >> 6, lane = tid & 63;
    if (lane == 0) {
        red[wave][0] = ax1; red[wave][1] = ay1;
        red[wave][2] = ax2; red[wave][3] = ay2;
    }
    __syncthreads();
    if (tid < 2) {  // tid 0 -> k1, tid 1 -> k2
        if (tid == 0 || !dup) {
            float rx = 0.f, ry = 0.f;
            #pragma unroll
            for (int w2 = 0; w2 < 8; ++w2) {
                rx += red[w2][tid * 2 + 0];
                ry += red[w2][tid * 2 + 1];
            }
            int k = tid ? k2 : k1;
            out[2 * k + 0] = rx;
            out[2 * k + 1] = ry;
        }
    }
}

extern "C" void kernel_launch(void* const* d_in, const int* in_sizes, int n_in,
                              void* d_out, int out_size, void* d_ws, size_t ws_size,
                              hipStream_t stream) {
    const float* ado    = (const float*)d_in[0];
    const float* ado_wo = (const float*)d_in[1];
    const float* pg     = (const float*)d_in[2];
    float* out  = (float*)d_out;
    float* ws   = (float*)d_ws;                    // 32768 floats = 128 KB
    float* coef = (float*)d_ws + TT * AA * 2;      // 32768 floats = 128 KB

    wscoef_kernel<<<AA * (TT / 64), 256, 0, stream>>>(ado, ado_wo, ws, coef);
    grad_kernel<<<512, 512, 0, stream>>>(pg, ws, coef, out);
}